// Round 1
// baseline (310.797 us; speedup 1.0000x reference)
//
#include <hip/hip_runtime.h>
#include <math.h>

// ============================================================================
// WaveletBasis: out[b,o] = sum_i basis(x[b,i]) . coeffs[i,o,:] + x @ base_weight
// Cast as bf16 MFMA GEMM: M=32768(B), N=64(O), K=1024*9 (8 basis slots + x).
// K ordering: k = i*9 + n.  W_ext[k][o] = coeffs[i,o,n] (n<8) | bw[i,o] (n==8)
// A_ext[b][k] = [1, s0, onehot2*s1, onehot4*s2, x]  -- all derived from
// j = clip(floor(8u),0,7), u = (tanh(x)+1)/2.
// ============================================================================

typedef __attribute__((ext_vector_type(8))) short short8;
typedef __attribute__((ext_vector_type(4))) float f32x4;

__device__ __forceinline__ unsigned short f2bf(float f) {
  unsigned int u = __float_as_uint(f);
  u += 0x7FFFu + ((u >> 16) & 1u);   // RNE; inputs are finite
  return (unsigned short)(u >> 16);
}

#define NSTEP 288   // K32 steps total (K = 9216)
#define CHUNKS 32   // feature chunks (32 features each)
#define CH 9        // K32 steps per chunk (288 k-values)

// ---------------------------------------------------------------------------
// K1: build W swizzled into MFMA B-fragment order.
// Wsw[(s*4+t)*64 + l] = 8 bf16: W_ext[s*32 + (l>>4)*8 + jj][t*16 + (l&15)]
// ---------------------------------------------------------------------------
__global__ __launch_bounds__(256) void build_w(const float* __restrict__ coeffs,
                                               const float* __restrict__ bw,
                                               uint4* __restrict__ Wsw) {
  const int l = threadIdx.x & 63;
  const int t = threadIdx.x >> 6;   // 0..3
  const int s = blockIdx.x;         // 0..287
  const int o = t * 16 + (l & 15);
  const int kb = s * 32 + (l >> 4) * 8;
  unsigned int dw[4];
#pragma unroll
  for (int jj = 0; jj < 8; ++jj) {
    int k = kb + jj;
    int i = k / 9;          // compiler emits magic-mul
    int n = k - i * 9;
    float v = (n < 8) ? coeffs[(i * 64 + o) * 8 + n] : bw[i * 64 + o];
    unsigned int h = f2bf(v);
    if (jj & 1) dw[jj >> 1] |= h << 16; else dw[jj >> 1] = h;
  }
  uint4 q; q.x = dw[0]; q.y = dw[1]; q.z = dw[2]; q.w = dw[3];
  Wsw[(s * 4 + t) * 64 + l] = q;
}

// ---------------------------------------------------------------------------
// K2: main GEMM. 512 blocks x 256 thr (4 waves). Block = 64 rows x 64 cols.
// LDS A-tile layout: Albuf[g*64 + m] (uint4 = 8 bf16), g = k-octet index
// in chunk (0..35), m = row (0..63). Conflict-free b128 reads/writes.
// ---------------------------------------------------------------------------
__global__ __launch_bounds__(256, 2) void wavelet_gemm(const float* __restrict__ x,
                                                       const uint4* __restrict__ Wsw,
                                                       float* __restrict__ out,
                                                       int out_size) {
  __shared__ uint4 Albuf[36 * 64];   // 36 KB
  const int tid = threadIdx.x;
  const int l = tid & 63;
  const int w = tid >> 6;            // wave 0..3 (16 rows each)
  const int m = tid & 63;            // builder row 0..63
  const int f8 = tid >> 6;           // builder feature-octet 0..3
  const long rowbase = (long)blockIdx.x * 64;

  f32x4 acc[4];
#pragma unroll
  for (int t = 0; t < 4; ++t) acc[t] = (f32x4){0.f, 0.f, 0.f, 0.f};

  // builder x pointer: x[(rowbase+m)*1024 + c*32 + f8*8 + ff]
  const float* xrow = x + (rowbase + m) * 1024 + f8 * 8;
  float4 xa = *(const float4*)(xrow);
  float4 xb = *(const float4*)(xrow + 4);

  const int q = l >> 4;
  const int mm = l & 15;
  const int rdoff = q * 64 + w * 16 + mm;   // + sl*256 per K32-step

  for (int c = 0; c < CHUNKS; ++c) {
    // ---- build A chunk (8 features -> 72 bf16 -> 9 x ds_write_b128) ----
    unsigned int dw[36];
    float xv[8];
    xv[0] = xa.x; xv[1] = xa.y; xv[2] = xa.z; xv[3] = xa.w;
    xv[4] = xb.x; xv[5] = xb.y; xv[6] = xb.z; xv[7] = xb.w;
#pragma unroll
    for (int ff = 0; ff < 8; ++ff) {
      float xf = xv[ff];
      // fast tanh: 1 - 2/(e^{2x}+1)
      float e = __expf(2.0f * xf);
      float tf = 1.0f - 2.0f / (e + 1.0f);
      float uf = (tf + 1.0f) * 0.5f;
      float t8 = uf * 8.0f;
      float rn = rintf(t8);
      if (__builtin_expect(fabsf(t8 - rn) < 3e-4f, 0)) {
        // near a bucket boundary: recompute at f64 quality, then replicate
        // the reference's f32 pipeline exactly
        tf = (float)tanh((double)xf);
        uf = (tf + 1.0f) * 0.5f;
        t8 = uf * 8.0f;
      }
      int j = (int)floorf(t8);
      j = j < 0 ? 0 : (j > 7 ? 7 : j);
      unsigned short sg0 = (j < 4) ? (unsigned short)0x3F80u : (unsigned short)0xBF80u;
      unsigned short sq1 = ((j >> 1) & 1) ? (unsigned short)0xBFB5u : (unsigned short)0x3FB5u; // ±sqrt2
      unsigned short sd2 = (j & 1) ? (unsigned short)0xC000u : (unsigned short)0x4000u;        // ±2
      int k1 = j >> 2, k2 = j >> 1;
      unsigned short v[9];
      v[0] = 0x3F80u; v[1] = sg0;
      v[2] = (k1 == 0) ? sq1 : (unsigned short)0;
      v[3] = (k1 == 1) ? sq1 : (unsigned short)0;
      v[4] = (k2 == 0) ? sd2 : (unsigned short)0;
      v[5] = (k2 == 1) ? sd2 : (unsigned short)0;
      v[6] = (k2 == 2) ? sd2 : (unsigned short)0;
      v[7] = (k2 == 3) ? sd2 : (unsigned short)0;
      v[8] = f2bf(xf);
#pragma unroll
      for (int n = 0; n < 9; ++n) {
        int si = 9 * ff + n;
        unsigned int hv = v[n];
        if (si & 1) dw[si >> 1] |= hv << 16; else dw[si >> 1] = hv;
      }
    }
#pragma unroll
    for (int gg = 0; gg < 9; ++gg) {
      uint4 qv;
      qv.x = dw[4 * gg]; qv.y = dw[4 * gg + 1];
      qv.z = dw[4 * gg + 2]; qv.w = dw[4 * gg + 3];
      Albuf[(f8 * 9 + gg) * 64 + m] = qv;
    }
    // prefetch next chunk's x while this chunk computes
    if (c + 1 < CHUNKS) {
      const float* xn = xrow + (c + 1) * 32;
      xa = *(const float4*)(xn);
      xb = *(const float4*)(xn + 4);
    }
    __syncthreads();
    // ---- MFMA over 9 K32-steps; B-frags direct from global (L2-hot) ----
#pragma unroll
    for (int sl = 0; sl < CH; ++sl) {
      int sg = c * CH + sl;
      short8 af = __builtin_bit_cast(short8, Albuf[sl * 256 + rdoff]);
      const uint4* wp = Wsw + (size_t)(sg * 4) * 64 + l;
      uint4 b0 = wp[0];
      uint4 b1 = wp[64];
      uint4 b2 = wp[128];
      uint4 b3 = wp[192];
      acc[0] = __builtin_amdgcn_mfma_f32_16x16x32_bf16(af, __builtin_bit_cast(short8, b0), acc[0], 0, 0, 0);
      acc[1] = __builtin_amdgcn_mfma_f32_16x16x32_bf16(af, __builtin_bit_cast(short8, b1), acc[1], 0, 0, 0);
      acc[2] = __builtin_amdgcn_mfma_f32_16x16x32_bf16(af, __builtin_bit_cast(short8, b2), acc[2], 0, 0, 0);
      acc[3] = __builtin_amdgcn_mfma_f32_16x16x32_bf16(af, __builtin_bit_cast(short8, b3), acc[3], 0, 0, 0);
    }
    __syncthreads();
  }

  // epilogue: C/D layout col = lane&15, row = (lane>>4)*4 + reg  [m89/m91]
  long rbase = rowbase + w * 16 + q * 4;
#pragma unroll
  for (int t = 0; t < 4; ++t) {
#pragma unroll
    for (int r = 0; r < 4; ++r) {
      out[(rbase + r) * 64 + t * 16 + mm] = acc[t][r];
    }
  }
  if (blockIdx.x == 0 && tid == 0) out[out_size - 1] = 0.0f;  // kl = 0
}

extern "C" void kernel_launch(void* const* d_in, const int* in_sizes, int n_in,
                              void* d_out, int out_size, void* d_ws, size_t ws_size,
                              hipStream_t stream) {
  const float* x      = (const float*)d_in[0];   // [32768,1024] f32
  const float* coeffs = (const float*)d_in[1];   // [1024,64,8] f32
  const float* bw     = (const float*)d_in[2];   // [1024,64] f32
  uint4* Wsw = (uint4*)d_ws;                     // needs 288*4*64*16 = 1.125 MiB
  float* out = (float*)d_out;                    // [32768*64 + 1]

  build_w<<<288, 256, 0, stream>>>(coeffs, bw, Wsw);
  wavelet_gemm<<<512, 256, 0, stream>>>(x, (const uint4*)Wsw, out, out_size);
}

// Round 2
// 307.072 us; speedup vs baseline: 1.0121x; 1.0121x over previous
//
#include <hip/hip_runtime.h>
#include <math.h>

// ============================================================================
// WaveletBasis as bf16 MFMA GEMM: M=32768(B), N=64(O), K=1024*9.
// K layout (free, build_w and gemm agree): 128 "runs" of 72 k-values, run R =
// features [8R, 8R+8). Within a run, feature pair p occupies shorts [18p,18p+18):
//   [basis(f_even) n=0..7 | x_even | x_odd | basis(f_odd) n=0..7]
// Chunk c = runs [4c,4c+4) = features [32c,32c+32) = 9 K32-steps.
// Step g=9c+j: lane-group q (=lane>>4) holds octet j of run 4c+q.
//
// K-SPLIT: wave w computes a full 64x64 partial over steps sl in {w,w+4,w+8};
// 4 partials reduced via LDS ds_add_f32. Rows/wave=64 -> B L2 traffic 576 MB
// (4x less than round 1). B is register-pipelined 2 steps deep; barriers are
// raw lgkmcnt(0)+s_barrier so VMEM prefetch survives them.
// ============================================================================

typedef __attribute__((ext_vector_type(8))) short short8;
typedef __attribute__((ext_vector_type(4))) float f32x4;

__device__ __forceinline__ unsigned int f2bf(float f) {
  unsigned int u = __float_as_uint(f);
  u += 0x7FFFu + ((u >> 16) & 1u);   // RNE; finite inputs
  return u >> 16;
}

// j = clip(floor(8u),0,7), u=(tanh(x)+1)/2, replicating the reference's f32
// pipeline at bucket boundaries (f64 tanh fallback).
__device__ __forceinline__ int bucket(float xf) {
  float e = __expf(2.0f * xf);
  float tf = 1.0f - 2.0f / (e + 1.0f);
  float t8 = (tf + 1.0f) * 4.0f;           // == ((tf+1)*0.5f)*8, exact pow2 muls
  float rn = rintf(t8);
  if (__builtin_expect(fabsf(t8 - rn) < 3e-4f, 0)) {
    tf = (float)tanh((double)xf);
    float uf = (tf + 1.0f) * 0.5f;
    t8 = uf * 8.0f;
  }
  int j = (int)floorf(t8);
  return j < 0 ? 0 : (j > 7 ? 7 : j);
}

// 4 dwords = 8 bf16 basis values (n=0..7) as a function of bucket j.
__device__ __forceinline__ void gen_basis(int j, unsigned int* d) {
  d[0] = (j < 4) ? 0x3F803F80u : 0xBF803F80u;                  // [phi=1, psi0=+-1]
  unsigned int sq1 = (j & 2) ? 0xBFB5u : 0x3FB5u;              // +-sqrt2
  d[1] = (j & 4) ? (sq1 << 16) : sq1;                          // one-hot k1=j>>2
  unsigned long long sd2 = (j & 1) ? 0xC000ull : 0x4000ull;    // +-2
  unsigned long long d23 = sd2 << ((j & 6) << 3);              // << 16*(j>>1)
  d[2] = (unsigned int)d23;
  d[3] = (unsigned int)(d23 >> 32);
}

#define BARRIER() __asm__ volatile("s_waitcnt lgkmcnt(0)\n\ts_barrier" ::: "memory")

// ---------------------------------------------------------------------------
// K1: W swizzle into MFMA B-fragment order under the run/pair K layout.
// Wsw[(g*4+t)*64 + l] = octet j=g%9 of run R=(g/9)*4+(l>>4), col o=t*16+(l&15)
// ---------------------------------------------------------------------------
__global__ __launch_bounds__(256) void build_w(const float* __restrict__ coeffs,
                                               const float* __restrict__ bw,
                                               uint4* __restrict__ Wsw) {
  const int l = threadIdx.x & 63;
  const int t = threadIdx.x >> 6;   // 0..3
  const int g = blockIdx.x;         // 0..287
  const int c = g / 9, j = g - c * 9;
  const int R = c * 4 + (l >> 4);
  const int o = t * 16 + (l & 15);
  unsigned int dwv[4];
#pragma unroll
  for (int jj = 0; jj < 8; ++jj) {
    int d = 8 * j + jj;             // run-local short index 0..71
    int p = d / 18;
    int e = d - p * 18;
    int f, n;
    if (e < 8)       { f = 8 * R + 2 * p;     n = e; }
    else if (e == 8) { f = 8 * R + 2 * p;     n = 8; }
    else if (e == 9) { f = 8 * R + 2 * p + 1; n = 8; }
    else             { f = 8 * R + 2 * p + 1; n = e - 10; }
    float v = (n < 8) ? coeffs[(f * 64 + o) * 8 + n] : bw[f * 64 + o];
    unsigned int h = f2bf(v);
    if (jj & 1) dwv[jj >> 1] |= h << 16; else dwv[jj >> 1] = h;
  }
  uint4 qq; qq.x = dwv[0]; qq.y = dwv[1]; qq.z = dwv[2]; qq.w = dwv[3];
  Wsw[(g * 4 + t) * 64 + l] = qq;
}

// ---------------------------------------------------------------------------
// Main loop, templated on steps-per-chunk for this wave (3 for w0, 2 for w1-3)
// ---------------------------------------------------------------------------
template <int NS>
__device__ __forceinline__ void run_main(const float* __restrict__ xrow,
                                         const uint4* __restrict__ Wsw,
                                         uint4* __restrict__ Albuf,
                                         f32x4* acc,
                                         int s0, int q, int mm, int m, int f8, int l) {
  uint4 bc[4], bn[4];
  {
    const uint4* wp0 = Wsw + (size_t)(s0 * 4) * 64 + l;         // flat step 0
    bc[0] = wp0[0]; bc[1] = wp0[64]; bc[2] = wp0[128]; bc[3] = wp0[192];
    const uint4* wp1 = Wsw + (size_t)((s0 + 4) * 4) * 64 + l;   // flat step 1
    bn[0] = wp1[0]; bn[1] = wp1[64]; bn[2] = wp1[128]; bn[3] = wp1[192];
  }
  float4 xa = *(const float4*)(xrow);
  float4 xb = *(const float4*)(xrow + 4);

  for (int c = 0; c < 32; ++c) {
    // ---------------- builder: 8 features -> 9 octets -> LDS ----------------
    unsigned int dw[36];
    float xv[8];
    xv[0] = xa.x; xv[1] = xa.y; xv[2] = xa.z; xv[3] = xa.w;
    xv[4] = xb.x; xv[5] = xb.y; xv[6] = xb.z; xv[7] = xb.w;
#pragma unroll
    for (int p = 0; p < 4; ++p) {
      int je = bucket(xv[2 * p]);
      int jo = bucket(xv[2 * p + 1]);
      gen_basis(je, &dw[9 * p]);
      dw[9 * p + 4] = f2bf(xv[2 * p]) | (f2bf(xv[2 * p + 1]) << 16);
      gen_basis(jo, &dw[9 * p + 5]);
    }
    uint4* wbase = Albuf + f8 * 64 + m;
#pragma unroll
    for (int gg = 0; gg < 9; ++gg) {
      uint4 qv; qv.x = dw[4 * gg]; qv.y = dw[4 * gg + 1];
      qv.z = dw[4 * gg + 2]; qv.w = dw[4 * gg + 3];
      wbase[gg * 256] = qv;                 // Albuf[(gg*4+f8)*64 + m]
    }
    BARRIER();                              // A visible; VMEM stays in flight
    if (c + 1 < 32) {                       // x prefetch overlaps MFMA phase
      const float* xn = xrow + (c + 1) * 32;
      xa = *(const float4*)(xn);
      xb = *(const float4*)(xn + 4);
    }
    // ---------------- MFMA: this wave's steps of chunk c --------------------
    const uint4* rbase = Albuf + q * 64 + mm;
#pragma unroll
    for (int i = 0; i < NS; ++i) {
      const int sl = s0 + 4 * i;
      short8 a0 = __builtin_bit_cast(short8, rbase[sl * 256 + 0]);
      short8 a1 = __builtin_bit_cast(short8, rbase[sl * 256 + 16]);
      short8 a2 = __builtin_bit_cast(short8, rbase[sl * 256 + 32]);
      short8 a3 = __builtin_bit_cast(short8, rbase[sl * 256 + 48]);
      // prefetch B two flat-steps ahead (pure function of step, barrier-free)
      uint4 b2[4];
      const int c2 = c + ((i + 2) >= NS ? 1 : 0);
      const int i2 = (i + 2) % NS;
      if (c2 < 32) {
        int g2 = c2 * 9 + s0 + 4 * i2;
        const uint4* wp = Wsw + (size_t)(g2 * 4) * 64 + l;
        b2[0] = wp[0]; b2[1] = wp[64]; b2[2] = wp[128]; b2[3] = wp[192];
      }
      short8 B0 = __builtin_bit_cast(short8, bc[0]);
      short8 B1 = __builtin_bit_cast(short8, bc[1]);
      short8 B2 = __builtin_bit_cast(short8, bc[2]);
      short8 B3 = __builtin_bit_cast(short8, bc[3]);
#pragma unroll
      for (int rt = 0; rt < 4; ++rt) {
        short8 af = (rt == 0) ? a0 : (rt == 1) ? a1 : (rt == 2) ? a2 : a3;
        acc[rt * 4 + 0] = __builtin_amdgcn_mfma_f32_16x16x32_bf16(af, B0, acc[rt * 4 + 0], 0, 0, 0);
        acc[rt * 4 + 1] = __builtin_amdgcn_mfma_f32_16x16x32_bf16(af, B1, acc[rt * 4 + 1], 0, 0, 0);
        acc[rt * 4 + 2] = __builtin_amdgcn_mfma_f32_16x16x32_bf16(af, B2, acc[rt * 4 + 2], 0, 0, 0);
        acc[rt * 4 + 3] = __builtin_amdgcn_mfma_f32_16x16x32_bf16(af, B3, acc[rt * 4 + 3], 0, 0, 0);
      }
      bc[0] = bn[0]; bc[1] = bn[1]; bc[2] = bn[2]; bc[3] = bn[3];
      bn[0] = b2[0]; bn[1] = b2[1]; bn[2] = b2[2]; bn[3] = b2[3];
    }
    BARRIER();                              // reads drained before next writes
  }
}

// ---------------------------------------------------------------------------
// K2: 512 blocks x 256 thr. Block = 64 rows x 64 cols, K split across 4 waves.
// ---------------------------------------------------------------------------
__global__ __launch_bounds__(256, 2) void wavelet_gemm(const float* __restrict__ x,
                                                       const uint4* __restrict__ Wsw,
                                                       float* __restrict__ out,
                                                       int out_size) {
  __shared__ uint4 Albuf[36 * 64];   // 36 KB; reused as padded C-reduce buffer
  const int tid = threadIdx.x;
  const int l = tid & 63;
  const int w = tid >> 6;            // wave 0..3 = K-quarter owner
  const int q = l >> 4;
  const int mm = l & 15;
  const int m = tid & 63;            // builder row
  const int f8 = tid >> 6;           // builder run-within-chunk
  const long rowbase = (long)blockIdx.x * 64;

  f32x4 acc[16];
#pragma unroll
  for (int i = 0; i < 16; ++i) acc[i] = (f32x4){0.f, 0.f, 0.f, 0.f};

  const float* xrow = x + (rowbase + m) * 1024 + f8 * 8;

  if (w == 0) run_main<3>(xrow, Wsw, Albuf, acc, 0, q, mm, m, f8, l);
  else        run_main<2>(xrow, Wsw, Albuf, acc, w, q, mm, m, f8, l);

  // ---------------- cross-wave K-reduction via LDS ds_add_f32 ---------------
  float* Cb = (float*)Albuf;                  // 64 rows x 68 cols (pad: 2-way=free)
  float4 z4; z4.x = 0.f; z4.y = 0.f; z4.z = 0.f; z4.w = 0.f;
  for (int i = tid; i < 64 * 17; i += 256) ((float4*)Cb)[i] = z4;
  BARRIER();
#pragma unroll
  for (int rt = 0; rt < 4; ++rt)
#pragma unroll
    for (int tt = 0; tt < 4; ++tt)
#pragma unroll
      for (int e = 0; e < 4; ++e)
        atomicAdd(Cb + (16 * rt + 4 * q + e) * 68 + 16 * tt + mm, acc[rt * 4 + tt][e]);
  BARRIER();

  // ---------------- coalesced store: contiguous float4 per instr ------------
  float4* O4 = (float4*)(out + (size_t)rowbase * 64);
#pragma unroll
  for (int i = 0; i < 4; ++i) {
    int F = i * 256 + tid;                    // float4 index 0..1023
    int row = F >> 4, col = (F & 15) * 4;
    O4[F] = *(float4*)(Cb + row * 68 + col);
  }
  if (blockIdx.x == 0 && tid == 0) out[out_size - 1] = 0.0f;  // kl = 0
}

extern "C" void kernel_launch(void* const* d_in, const int* in_sizes, int n_in,
                              void* d_out, int out_size, void* d_ws, size_t ws_size,
                              hipStream_t stream) {
  const float* x      = (const float*)d_in[0];   // [32768,1024] f32
  const float* coeffs = (const float*)d_in[1];   // [1024,64,8] f32
  const float* bw     = (const float*)d_in[2];   // [1024,64] f32
  uint4* Wsw = (uint4*)d_ws;                     // 288*4*64*16 = 1.125 MiB
  float* out = (float*)d_out;

  build_w<<<288, 256, 0, stream>>>(coeffs, bw, Wsw);
  wavelet_gemm<<<512, 256, 0, stream>>>(x, (const uint4*)Wsw, out, out_size);
}

// Round 3
// 232.787 us; speedup vs baseline: 1.3351x; 1.3191x over previous
//
#include <hip/hip_runtime.h>
#include <math.h>

// ============================================================================
// WaveletBasis as bf16 MFMA GEMM: M=32768(B), N=64(O), K=1024*9.
// K layout: 128 "runs" of 72 k-values, run R = features [8R,8R+8). Within a
// run, feature pair p occupies shorts [18p,18p+18):
//   [basis(f_even) n=0..7 | x_even | x_odd | basis(f_odd) n=0..7]
// Chunk c = runs [4c,4c+4) = features [32c,32c+32) = 9 K32-steps.
// Step g=9c+j: lane-group q(=l>>4) holds octet j of run 4c+q.
// K-split: wave w owns steps {w, w+4, w+8} of each chunk (full 64x64 partial);
// partials reduced via LDS at the end.
//
// ROUND 3: double-buffered A + ONE barrier per chunk -> builder VALU, B L2
// loads and MFMA of consecutive chunks overlap (round 1/2 were phase-bound:
// MfmaUtil 9%, VALUBusy 29%, occupancy 20% => mostly stall). Builder common
// path made branch-free (single rare fixer block, window 3e-5). Epilogue
// atomics replaced by per-wave LDS partials + register reduction.
// ============================================================================

typedef __attribute__((ext_vector_type(8))) short short8;
typedef __attribute__((ext_vector_type(4))) float f32x4;

__device__ __forceinline__ unsigned int f2bf(float f) {
  unsigned int u = __float_as_uint(f);
  u += 0x7FFFu + ((u >> 16) & 1u);   // RNE; finite inputs
  return u >> 16;
}

// 4 dwords = 8 bf16 basis values (n=0..7) as a function of bucket j.
__device__ __forceinline__ void gen_basis(int j, unsigned int* d) {
  d[0] = (j < 4) ? 0x3F803F80u : 0xBF803F80u;                  // [phi=1, psi0=+-1]
  unsigned int sq1 = (j & 2) ? 0xBFB5u : 0x3FB5u;              // +-sqrt2
  d[1] = (j & 4) ? (sq1 << 16) : sq1;                          // one-hot k1=j>>2
  unsigned long long sd2 = (j & 1) ? 0xC000ull : 0x4000ull;    // +-2
  unsigned long long d23 = sd2 << ((j & 6) << 3);              // << 16*(j>>1)
  d[2] = (unsigned int)d23;
  d[3] = (unsigned int)(d23 >> 32);
}

#define BARRIER() __asm__ volatile("s_waitcnt lgkmcnt(0)\n\ts_barrier" ::: "memory")

// ---------------------------------------------------------------------------
// Builder: 8 features (one run) -> 9 uint4 -> LDS at dst[gg*256].
// Common path is branch-free: fast tanh via exp+rcp; lanes within 3e-5 of a
// bucket boundary (fast-vs-ref t8 error <= ~6e-6) fixed in a rare cold block
// that replicates the reference f32 pipeline after an f64 tanh.
// ---------------------------------------------------------------------------
__device__ __forceinline__ void build_chunk(const float4& xa, const float4& xb,
                                            uint4* __restrict__ dst) {
  float xv[8];
  xv[0] = xa.x; xv[1] = xa.y; xv[2] = xa.z; xv[3] = xa.w;
  xv[4] = xb.x; xv[5] = xb.y; xv[6] = xb.z; xv[7] = xb.w;
  float t8v[8];
  unsigned int bad = 0;
#pragma unroll
  for (int ff = 0; ff < 8; ++ff) {
    float e = __expf(2.0f * xv[ff]);                 // t8 = 8*e/(e+1) = 8 - 8/(e+1)
    float r = __builtin_amdgcn_rcpf(e + 1.0f);
    float t8 = __builtin_fmaf(-8.0f, r, 8.0f);
    float rn = rintf(t8);
    if (fabsf(t8 - rn) < 3e-5f) bad |= 1u << ff;
    t8v[ff] = t8;
  }
  if (__builtin_expect(bad != 0, 0)) {
#pragma unroll
    for (int ff = 0; ff < 8; ++ff)
      if (bad & (1u << ff)) {
        float tf = (float)tanh((double)xv[ff]);      // ref-fidelity fallback
        t8v[ff] = ((tf + 1.0f) * 0.5f) * 8.0f;       // exact ref f32 pipeline
      }
  }
  unsigned int dw[36];
#pragma unroll
  for (int p = 0; p < 4; ++p) {
    int je = (int)t8v[2 * p];     je = je > 7 ? 7 : je;   // t8 in [0,8]
    int jo = (int)t8v[2 * p + 1]; jo = jo > 7 ? 7 : jo;
    gen_basis(je, &dw[9 * p]);
    dw[9 * p + 4] = f2bf(xv[2 * p]) | (f2bf(xv[2 * p + 1]) << 16);
    gen_basis(jo, &dw[9 * p + 5]);
  }
#pragma unroll
  for (int gg = 0; gg < 9; ++gg) {
    uint4 qv; qv.x = dw[4 * gg]; qv.y = dw[4 * gg + 1];
    qv.z = dw[4 * gg + 2]; qv.w = dw[4 * gg + 3];
    dst[gg * 256] = qv;
  }
}

// ---------------------------------------------------------------------------
// K1: W swizzle into MFMA B-fragment order under the run/pair K layout.
// Wsw[(g*4+t)*64 + l] = octet j=g%9 of run R=(g/9)*4+(l>>4), col o=t*16+(l&15)
// ---------------------------------------------------------------------------
__global__ __launch_bounds__(256) void build_w(const float* __restrict__ coeffs,
                                               const float* __restrict__ bw,
                                               uint4* __restrict__ Wsw) {
  const int l = threadIdx.x & 63;
  const int t = threadIdx.x >> 6;   // 0..3
  const int g = blockIdx.x;         // 0..287
  const int c = g / 9, j = g - c * 9;
  const int R = c * 4 + (l >> 4);
  const int o = t * 16 + (l & 15);
  unsigned int dwv[4];
#pragma unroll
  for (int jj = 0; jj < 8; ++jj) {
    int d = 8 * j + jj;             // run-local short index 0..71
    int p = d / 18;
    int e = d - p * 18;
    int f, n;
    if (e < 8)       { f = 8 * R + 2 * p;     n = e; }
    else if (e == 8) { f = 8 * R + 2 * p;     n = 8; }
    else if (e == 9) { f = 8 * R + 2 * p + 1; n = 8; }
    else             { f = 8 * R + 2 * p + 1; n = e - 10; }
    float v = (n < 8) ? coeffs[(f * 64 + o) * 8 + n] : bw[f * 64 + o];
    unsigned int h = f2bf(v);
    if (jj & 1) dwv[jj >> 1] |= h << 16; else dwv[jj >> 1] = h;
  }
  uint4 qq; qq.x = dwv[0]; qq.y = dwv[1]; qq.z = dwv[2]; qq.w = dwv[3];
  Wsw[(g * 4 + t) * 64 + l] = qq;
}

// ---------------------------------------------------------------------------
// Main loop: double-buffered A chunk, single barrier per chunk.
// ---------------------------------------------------------------------------
template <int NS>
__device__ __forceinline__ void run_main(const float* __restrict__ xrow,
                                         const uint4* __restrict__ Wsw,
                                         uint4* __restrict__ Albuf,
                                         f32x4* acc,
                                         int s0, int q, int mm, int bdoff, int l) {
  float4 xa = *(const float4*)(xrow);
  float4 xb = *(const float4*)(xrow + 4);
  build_chunk(xa, xb, Albuf + bdoff);          // chunk 0 -> buf0
  xa = *(const float4*)(xrow + 32);            // x for chunk 1
  xb = *(const float4*)(xrow + 36);
  BARRIER();
  for (int c = 0; c < 32; ++c) {
    uint4* cur = Albuf + (c & 1) * 2304;
    uint4* nxt = Albuf + ((c + 1) & 1) * 2304;
    // ---- B for this chunk's NS steps (L2-hot; latency hidden by builder) ---
    uint4 Bv[NS][4];
#pragma unroll
    for (int i = 0; i < NS; ++i) {
      const uint4* wp = Wsw + (size_t)((c * 9 + s0 + 4 * i) * 256) + l;
      Bv[i][0] = wp[0]; Bv[i][1] = wp[64]; Bv[i][2] = wp[128]; Bv[i][3] = wp[192];
    }
    // ---- builder for chunk c+1 into the other buffer ----------------------
    if (c + 1 < 32) {
      build_chunk(xa, xb, nxt + bdoff);
      if (c + 2 < 32) {
        xa = *(const float4*)(xrow + (c + 2) * 32);
        xb = *(const float4*)(xrow + (c + 2) * 32 + 4);
      }
    }
    // ---- MFMA: this wave's steps of chunk c -------------------------------
#pragma unroll
    for (int i = 0; i < NS; ++i) {
      const int sl = s0 + 4 * i;
      const uint4* rb = cur + sl * 256 + q * 64 + mm;
      short8 a0 = __builtin_bit_cast(short8, rb[0]);
      short8 a1 = __builtin_bit_cast(short8, rb[16]);
      short8 a2 = __builtin_bit_cast(short8, rb[32]);
      short8 a3 = __builtin_bit_cast(short8, rb[48]);
#pragma unroll
      for (int t = 0; t < 4; ++t) {
        short8 Bt = __builtin_bit_cast(short8, Bv[i][t]);
        acc[0 * 4 + t] = __builtin_amdgcn_mfma_f32_16x16x32_bf16(a0, Bt, acc[0 * 4 + t], 0, 0, 0);
        acc[1 * 4 + t] = __builtin_amdgcn_mfma_f32_16x16x32_bf16(a1, Bt, acc[1 * 4 + t], 0, 0, 0);
        acc[2 * 4 + t] = __builtin_amdgcn_mfma_f32_16x16x32_bf16(a2, Bt, acc[2 * 4 + t], 0, 0, 0);
        acc[3 * 4 + t] = __builtin_amdgcn_mfma_f32_16x16x32_bf16(a3, Bt, acc[3 * 4 + t], 0, 0, 0);
      }
    }
    BARRIER();   // writes to nxt visible, reads of cur drained; VMEM in flight
  }
}

// ---------------------------------------------------------------------------
// K2: 512 blocks x 256 thr. Block = 64 rows x 64 cols, K split across 4 waves.
// LDS: 2 x 36 KB A double-buffer (reused as 64 KB partial-C at the end).
// ---------------------------------------------------------------------------
__global__ __launch_bounds__(256, 2) void wavelet_gemm(const float* __restrict__ x,
                                                       const uint4* __restrict__ Wsw,
                                                       float* __restrict__ out,
                                                       int out_size) {
  __shared__ uint4 Albuf[2 * 9 * 4 * 64];   // 72 KB
  const int tid = threadIdx.x;
  const int l = tid & 63;
  const int w = tid >> 6;            // wave 0..3 = K-quarter owner / builder run
  const int q = l >> 4;
  const int mm = l & 15;
  const int m = tid & 63;            // builder row
  const int bdoff = w * 64 + m;      // builder LDS offset (f8*64 + m)
  const long rowbase = (long)blockIdx.x * 64;

  f32x4 acc[16];
#pragma unroll
  for (int i = 0; i < 16; ++i) acc[i] = (f32x4){0.f, 0.f, 0.f, 0.f};

  const float* xrow = x + (rowbase + m) * 1024 + w * 8;

  if (w == 0) run_main<3>(xrow, Wsw, Albuf, acc, 0, q, mm, bdoff, l);
  else        run_main<2>(xrow, Wsw, Albuf, acc, w, q, mm, bdoff, l);

  // ---- cross-wave K-reduction: per-wave partials in LDS (transposed) ------
  // P[w][col][row]: f32x4 of 4 consecutive rows per store -> 16 ds_write_b128
  float* P = (float*)Albuf;                   // 4 * 4096 floats = 64 KB
  float* W = P + w * 4096;
#pragma unroll
  for (int rt = 0; rt < 4; ++rt)
#pragma unroll
    for (int tt = 0; tt < 4; ++tt)
      *(f32x4*)(W + (16 * tt + mm) * 64 + 16 * rt + 4 * q) = acc[rt * 4 + tt];
  BARRIER();

  // ---- reduce 4 partials in registers, store (wave stores 256B runs) ------
  const int col = tid & 63;
  float* og = out + (size_t)rowbase * 64;
#pragma unroll
  for (int s = 0; s < 4; ++s) {
    int rg = s * 4 + (tid >> 6);              // row-group 0..15 (rows 4rg..4rg+4)
    f32x4 v = *(f32x4*)(P + 0 * 4096 + col * 64 + 4 * rg);
    v = v + *(f32x4*)(P + 1 * 4096 + col * 64 + 4 * rg);
    v = v + *(f32x4*)(P + 2 * 4096 + col * 64 + 4 * rg);
    v = v + *(f32x4*)(P + 3 * 4096 + col * 64 + 4 * rg);
#pragma unroll
    for (int r = 0; r < 4; ++r)
      og[(4 * rg + r) * 64 + col] = v[r];
  }
  if (blockIdx.x == 0 && tid == 0) out[out_size - 1] = 0.0f;  // kl = 0
}

extern "C" void kernel_launch(void* const* d_in, const int* in_sizes, int n_in,
                              void* d_out, int out_size, void* d_ws, size_t ws_size,
                              hipStream_t stream) {
  const float* x      = (const float*)d_in[0];   // [32768,1024] f32
  const float* coeffs = (const float*)d_in[1];   // [1024,64,8] f32
  const float* bw     = (const float*)d_in[2];   // [1024,64] f32
  uint4* Wsw = (uint4*)d_ws;                     // 288*4*64*16 = 1.125 MiB
  float* out = (float*)d_out;

  build_w<<<288, 256, 0, stream>>>(coeffs, bw, Wsw);
  wavelet_gemm<<<512, 256, 0, stream>>>(x, (const uint4*)Wsw, out, out_size);
}